// Round 1
// baseline (4414.342 us; speedup 1.0000x reference)
//
#include <hip/hip_runtime.h>

#define EPSV 1e-4f

__device__ __forceinline__ float bperm(int addr4, float v) {
  return __int_as_float(__builtin_amdgcn_ds_bpermute(addr4, __float_as_int(v)));
}

// variable-index read of a register array via cndmask chain (stays in VGPRs)
template<int N>
__device__ __forceinline__ float selN(const float (&a)[N], int idx) {
  float r = a[0];
#pragma unroll
  for (int k = 1; k < N; ++k) r = (idx == k) ? a[k] : r;
  return r;
}

// Parallel cyclic Jacobi, circle-method tournament with fixed physical pairs
// (i, N-1-i). Lane l (group-local) holds column l of A and row l of V in
// registers. Round body is round-invariant; after each full sweep (N-1
// rounds) labels coincide with slots again.
template<int N>
__device__ void jacobi_eig(float (&a)[N], float (&v)[N], int l, int base4,
                           bool laneValid, float tolsq, int maxSweeps)
{
  constexpr int NH = N / 2;
  const int partner = N - 1 - l;
  const int pslot = (l < NH) ? l : partner;
  const int qslot = N - 1 - pslot;
  const int p4 = base4 + 4 * pslot;
  const int q4 = base4 + 4 * qslot;
  const int pr4 = base4 + 4 * partner;
  const int srcl = (l == 0) ? 0 : ((l == 1) ? (N - 1) : (l - 1));
  const int src4 = base4 + 4 * srcl;
  const bool isP = (l < NH);

  float dval = selN<N>(a, l);   // own diagonal, maintained incrementally
  int sweep = 0;
  while (true) {
    float offAcc = 0.0f;
    for (int r = 0; r < N - 1; ++r) {
      float anti = selN<N>(a, partner);       // A[partner][l] == A[l][partner]
      float app = bperm(p4, dval);            // consistent (c,s) on both lanes
      float aqq = bperm(q4, dval);
      float apq = bperm(p4, anti);

      float absq = fabsf(apq);
      bool ok = absq > 1e-28f;
      float apqs = ok ? apq : 1.0f;
      float theta = 0.5f * (aqq - app) / apqs;
      float tt = 1.0f / (fabsf(theta) + sqrtf(theta * theta + 1.0f));
      tt = (theta < 0.0f) ? -tt : tt;
      tt = ok ? tt : 0.0f;
      float c = 1.0f / sqrtf(tt * tt + 1.0f);  // IEEE sqrt/div: keep backward
      float s = tt * c;                        // error at fp32 floor
      offAcc += laneValid ? apq * apq : 0.0f;  // == ||offdiag||_F^2 per sweep

      // column update: A <- A*G (my column combines with partner's)
      float seff = isP ? -s : s;
#pragma unroll
      for (int k = 0; k < N; ++k) {
        float pc = bperm(pr4, a[k]);
        a[k] = c * a[k] + seff * pc;
      }
      // row update A <- G^T*A, plus V <- V*G (V rows: shuffle-free)
#pragma unroll
      for (int i = 0; i < NH; ++i) {
        float ci = bperm(base4 + 4 * i, c);
        float si = bperm(base4 + 4 * i, s);
        float x = a[i], y = a[N - 1 - i];
        a[i]         = ci * x - si * y;
        a[N - 1 - i] = si * x + ci * y;
        float xv = v[i], yv = v[N - 1 - i];
        v[i]         = ci * xv - si * yv;
        v[N - 1 - i] = si * xv + ci * yv;
      }
      float dnew = isP ? (app - tt * apq) : (aqq + tt * apq);

      // tournament permutation: slot0 fixed, tail rotated (same sigma for
      // rows, columns, and V's column labels)
      float tmp[N];
#pragma unroll
      for (int k = 0; k < N; ++k) tmp[k] = bperm(src4, a[k]);
      a[0] = tmp[0];
      a[1] = tmp[N - 1];
#pragma unroll
      for (int k = 2; k < N; ++k) a[k] = tmp[k - 1];
      float xl = v[N - 1];
#pragma unroll
      for (int k = N - 1; k >= 2; --k) v[k] = v[k - 1];
      v[1] = xl;
      dval = bperm(src4, dnew);
    }
    ++sweep;
#pragma unroll
    for (int m = 1; m < 64; m <<= 1) offAcc += __shfl_xor(offAcc, m);
    if (sweep >= maxSweeps || offAcc < tolsq) break;   // wave-uniform
  }
}

// block = 256 threads = 4 waves; each wave owns 3 matrices (20 lanes each,
// lanes 60..63 are harmless shadows of group 2: they never write LDS/global
// and are never bpermute sources for real lanes).
__global__ __launch_bounds__(256, 3)
void spdnet_kernel(const float* __restrict__ X, const float* __restrict__ W1g,
                   const float* __restrict__ W2g, float* __restrict__ out,
                   int nBatch)
{
  __shared__ __align__(16) float sW1[20 * 32];       // padded rows
  __shared__ __align__(16) float sW2[15 * 20];
  __shared__ __align__(16) float sS[4 * 3 * 964];    // per-wave, per-group 964f

  const int tid = threadIdx.x;
  const int wave = tid >> 6;
  const int lane = tid & 63;
  const int grp = lane / 20;          // 0..3 (3 = shadow)
  const int l = lane - grp * 20;      // 0..19
  const int g3 = (grp < 3) ? grp : 2;
  const bool activeG = (grp < 3);
  const int wstart = blockIdx.x * 12 + wave * 3;
  const int bm = wstart + g3;
  const bool valid = activeG && (bm < nBatch);
  const int base4 = g3 * 80;          // group base lane * 4 bytes
  float* sSw = sS + wave * (3 * 964);
  float* Sm = sSw + g3 * 964;         // this group's scratch region

  for (int i = tid; i < 600; i += 256) sW1[(i / 30) * 32 + (i % 30)] = W1g[i];
  for (int i = tid; i < 300; i += 256) sW2[i] = W2g[i];

  // stage this wave's X matrices (coalesced), rows padded to 32
  int nm = nBatch - wstart; nm = nm < 0 ? 0 : (nm > 3 ? 3 : nm);
  const float* Xg = X + (size_t)wstart * 900;
  for (int idx = lane; idx < nm * 900; idx += 64) {
    int m = idx / 900;
    int rem = idx - m * 900;
    int r = rem / 30;
    int kk = rem - r * 30;
    sSw[m * 964 + r * 32 + kk] = Xg[idx];
  }
  __syncthreads();

  // S = sym(X), in place
  for (int t0 = lane; t0 < 2700; t0 += 64) {
    int m = t0 / 900;
    int rem = t0 - m * 900;
    int i = rem / 30;
    int j = rem - i * 30;
    if (i < j && m < nm) {
      float* Sp = sSw + m * 964;
      float x = Sp[i * 32 + j], y = Sp[j * 32 + i];
      float h = 0.5f * (x + y);
      Sp[i * 32 + j] = h;
      Sp[j * 32 + i] = h;
    }
  }
  __syncthreads();

  // W1 row l from global (float2: rows are only 8B-aligned)
  float w1r[30];
  {
    const float2* wr = (const float2*)(W1g + l * 30);
#pragma unroll
    for (int k2 = 0; k2 < 15; ++k2) {
      float2 q = wr[k2];
      w1r[2 * k2] = q.x; w1r[2 * k2 + 1] = q.y;
    }
  }
  // t = S * w1_row(l)   (broadcast LDS reads within group; groups offset 4 banks)
  float tcol[30];
#pragma unroll
  for (int r = 0; r < 30; ++r) {
    const float* row = Sm + r * 32;
    const float4* row4 = (const float4*)row;
    float acc = 0.0f;
#pragma unroll
    for (int k4 = 0; k4 < 7; ++k4) {
      float4 q = row4[k4];
      acc += q.x * w1r[4 * k4] + q.y * w1r[4 * k4 + 1] +
             q.z * w1r[4 * k4 + 2] + q.w * w1r[4 * k4 + 3];
    }
    acc += row[28] * w1r[28] + row[29] * w1r[29];
    tcol[r] = acc;
  }
  // a = column l of Y1 = W1*t  (+ eps I); V = I (rows)
  float a[20], v[20];
#pragma unroll
  for (int i = 0; i < 20; ++i) {
    const float* wrow = sW1 + i * 32;
    const float4* w4 = (const float4*)wrow;
    float acc = 0.0f;
#pragma unroll
    for (int k4 = 0; k4 < 7; ++k4) {
      float4 q = w4[k4];
      acc += q.x * tcol[4 * k4] + q.y * tcol[4 * k4 + 1] +
             q.z * tcol[4 * k4 + 2] + q.w * tcol[4 * k4 + 3];
    }
    acc += wrow[28] * tcol[28] + wrow[29] * tcol[29];
    a[i] = acc + ((i == l) ? EPSV : 0.0f);
    v[i] = (i == l) ? 1.0f : 0.0f;
  }

  jacobi_eig<20>(a, v, l, base4, valid, 2.0e-9f, 12);

  float lam1 = selN<20>(a, l);
  float gs = sqrtf(fmaxf(lam1, EPSV));

  // write V rows; then each lane grabs eigenvector column l
  float* Vl = Sm;                       // 20 x 21 (S is dead)
  if (activeG) {
#pragma unroll
    for (int k = 0; k < 20; ++k) Vl[l * 21 + k] = v[k];
  }
  __syncthreads();
  float vcol[20];
#pragma unroll
  for (int r = 0; r < 20; ++r) vcol[r] = Vl[r * 21 + l];
  // u_l = sqrt(g_l) * W2 * v_l  ->  Ut[i][l]
  float* Ut = Sm + 448;                 // 15 x 20
  float b[15];
#pragma unroll
  for (int i = 0; i < 15; ++i) {
    const float4* w2r = (const float4*)(sW2 + i * 20);
    float acc = 0.0f;
#pragma unroll
    for (int r4 = 0; r4 < 5; ++r4) {
      float4 q = w2r[r4];
      acc += q.x * vcol[4 * r4] + q.y * vcol[4 * r4 + 1] +
             q.z * vcol[4 * r4 + 2] + q.w * vcol[4 * r4 + 3];
    }
    b[i] = acc;
  }
  if (activeG) {
#pragma unroll
    for (int i = 0; i < 15; ++i) Ut[i * 20 + l] = gs * b[i];
  }
  __syncthreads();

  // Y2 (padded to 16x16, dummy row/col 15 = 0): a2[r] = <Ut[r][:], Ut[l2][:]>
  const int l2 = l & 15;
  float myrow[20];
  {
    const float4* mr = (const float4*)(Ut + ((l2 < 15) ? l2 : 0) * 20);
    float msk = (l2 < 15) ? 1.0f : 0.0f;
#pragma unroll
    for (int r4 = 0; r4 < 5; ++r4) {
      float4 q = mr[r4];
      myrow[4 * r4]     = q.x * msk; myrow[4 * r4 + 1] = q.y * msk;
      myrow[4 * r4 + 2] = q.z * msk; myrow[4 * r4 + 3] = q.w * msk;
    }
  }
  float a2[16], v2[16];
  a2[15] = 0.0f;
#pragma unroll
  for (int r = 0; r < 15; ++r) {
    const float4* ur = (const float4*)(Ut + r * 20);
    float acc = 0.0f;
#pragma unroll
    for (int r4 = 0; r4 < 5; ++r4) {
      float4 q = ur[r4];
      acc += q.x * myrow[4 * r4] + q.y * myrow[4 * r4 + 1] +
             q.z * myrow[4 * r4 + 2] + q.w * myrow[4 * r4 + 3];
    }
    a2[r] = acc + ((r == l2) ? EPSV : 0.0f);
  }
#pragma unroll
  for (int k = 0; k < 16; ++k) v2[k] = (k == l2) ? 1.0f : 0.0f;

  jacobi_eig<16>(a2, v2, l2, base4, valid && (l < 16), 3.0e-10f, 12);

  float lam2 = selN<16>(a2, l2);
  float h = logf(fmaxf(lam2, EPSV));   // fused reeig+logeig: log(max(mu,eps))

  __syncthreads();
  float* Wl = Sm;                       // 16 x 20 (Vl dead)
  float* hl = Sm + 768;                 // 16
  if (activeG && l < 16) {
#pragma unroll
    for (int k = 0; k < 16; ++k) Wl[l2 * 20 + k] = v2[k];
    hl[l2] = h;
  }
  __syncthreads();

  // M[i][j] = sum_k h_k V2[i][k] V2[j][k]; lane j=l stores rows i<=j of triu
  if (valid && l < 15) {
    float wj[15], hw[15];
#pragma unroll
    for (int k = 0; k < 15; ++k) wj[k] = Wl[l * 20 + k];
#pragma unroll
    for (int k = 0; k < 15; ++k) hw[k] = hl[k] * wj[k];
    float* og = out + (size_t)bm * 120;
#pragma unroll
    for (int i = 0; i < 15; ++i) {
      const float* wr = Wl + i * 20;
      float acc = 0.0f;
#pragma unroll
      for (int k = 0; k < 15; ++k) acc += hw[k] * wr[k];
      if (i <= l) og[15 * i - (i * (i - 1)) / 2 + (l - i)] = acc;
    }
  }
}

extern "C" void kernel_launch(void* const* d_in, const int* in_sizes, int n_in,
                              void* d_out, int out_size, void* d_ws, size_t ws_size,
                              hipStream_t stream) {
  const float* X  = (const float*)d_in[0];
  const float* W1 = (const float*)d_in[1];
  const float* W2 = (const float*)d_in[2];
  float* out = (float*)d_out;
  int nBatch = in_sizes[0] / 900;
  int nBlocks = (nBatch + 11) / 12;   // 12 matrices per 256-thread block
  spdnet_kernel<<<nBlocks, 256, 0, stream>>>(X, W1, W2, out, nBatch);
}